// Round 6
// baseline (298.372 us; speedup 1.0000x reference)
//
#include <hip/hip_runtime.h>
#include <hip/hip_bf16.h>

// MoE FFN: T=4096, H=I=1024, E=8, top-2. Inputs f32, output f32.
// Fast path (ws>=72.2MB): memset(counts) -> prep_all(cvtW via global_load_lds
// staged f32 tiles + swizzled-source transpose; cvtX; router) -> GEMM1
// (gate+up+SiLU, BM=256 8-wave, counted-vmcnt dbuf) -> Hbuf(bf16) -> GEMM2
// (down, same) -> Acc(bf16, aliases dead WtU) -> combine(f32).
// Fallback: R5 2-pass f32-staging path.

#define T_TOK 4096
#define HDIM  1024
#define NEXP  8
#define RROWS (T_TOK * 2)
#define MAXPE T_TOK

typedef unsigned short u16;
typedef short v8s __attribute__((ext_vector_type(8)));
typedef float v4f __attribute__((ext_vector_type(4)));
typedef __attribute__((address_space(3))) unsigned int as3_u32;
typedef const __attribute__((address_space(1))) unsigned int as1_u32c;

__device__ __forceinline__ float b2f(u16 u) {
    union { unsigned int i; float f; } v; v.i = ((unsigned int)u) << 16; return v.f;
}
__device__ __forceinline__ u16 f2b(float f) {
    union { float f; unsigned int i; } v; v.f = f;
    unsigned int x = v.i;
    return (u16)((x + 0x7FFFu + ((x >> 16) & 1u)) >> 16);
}
__device__ __forceinline__ unsigned int pack2(float a, float b) {
    return (unsigned int)f2b(a) | ((unsigned int)f2b(b) << 16);
}
__device__ __forceinline__ void stage16(const u16* g, u16* l) {
    __builtin_amdgcn_global_load_lds((as1_u32c*)g, (as3_u32*)l, 16, 0, 0);
}

// ---------------- prep_all ----------------
// blocks 0..2047:    cvtWU (64n x 128k tiles, 256/expert)
// blocks 2048..3071: cvtWD (64n x 128k tiles, 128/expert)
// blocks 3072..3583: cvtX
// blocks 3584..3599: router + bucket
// cvtW path: stage the f32 tile into LDS via 8 async global_load_lds per wave
// (zero VGPR, deep vmcnt) with XOR-preswizzled SOURCE addresses so the
// transposed (column) read is bank-conflict-free; then read+pack+store.
// Swizzle: slot(ng,k) = ng ^ m(k), m(k) = (k&15) ^ (((k>>5)&3)<<2) (involution).
__global__ __launch_bounds__(256)
void prep_all(const float* __restrict__ X, const float* __restrict__ RL,
              const float* __restrict__ WU, const float* __restrict__ WD,
              u16* __restrict__ Xb, u16* __restrict__ WtU, u16* __restrict__ WtD,
              int* __restrict__ ids, float* __restrict__ wts,
              int* __restrict__ counts, int* __restrict__ rowbuf) {
    __shared__ __align__(16) float smf[128 * 64];    // 32 KB f32 tile [k][n-swz]
    const int bx = blockIdx.x;
    const int tid = threadIdx.x;

    if (bx < 3072) {
        const float* Wb; u16* Wtb; int N, e, nt, kt;
        if (bx < 2048) {
            e = bx >> 8; int r = bx & 255;           // 32 n-tiles x 8 k-tiles
            nt = r >> 3; kt = r & 7;
            Wb = WU + (size_t)e * 1024 * 2048; Wtb = WtU + (size_t)e * 2048 * 1024; N = 2048;
        } else {
            int b = bx - 2048;
            e = b >> 7; int r = b & 127;             // 16 n-tiles x 8 k-tiles
            nt = r >> 3; kt = r & 7;
            Wb = WD + (size_t)e * 1024 * 1024; Wtb = WtD + (size_t)e * 1024 * 1024; N = 1024;
        }
        const int n0 = nt * 64, k0 = kt * 128;
        const int wv = tid >> 6, l = tid & 63;
#pragma unroll
        for (int i = 0; i < 8; i++) {
            int reg = wv * 8 + i;                    // 0..31, 4 k-rows each
            int k = reg * 4 + (l >> 4);              // 0..127
            int c = l & 15;                          // LDS 16B slot within row
            int ng = c ^ (k & 15) ^ (((k >> 5) & 3) << 2);
            stage16((const u16*)(Wb + (size_t)(k0 + k) * N + n0 + 4 * ng),
                    (u16*)smf + reg * 512 + l * 8);
        }
        __syncthreads();                             // drains vmcnt, tile ready
        const int n_l = tid >> 2, q = tid & 3;       // row n_l, k-chunk q (32 k)
        const int ng = n_l >> 2, sub = n_l & 3;
        u16* dst = Wtb + (size_t)(n0 + n_l) * 1024 + k0 + q * 32;
#pragma unroll
        for (int c8 = 0; c8 < 4; c8++) {
            float v[8];
#pragma unroll
            for (int j = 0; j < 8; j++) {
                int k = q * 32 + c8 * 8 + j;
                int sw = ng ^ (k & 15) ^ (((k >> 5) & 3) << 2);
                v[j] = smf[k * 64 + sw * 4 + sub];
            }
            uint4 o;
            o.x = pack2(v[0], v[1]); o.y = pack2(v[2], v[3]);
            o.z = pack2(v[4], v[5]); o.w = pack2(v[6], v[7]);
            *(uint4*)(dst + c8 * 8) = o;
        }
    } else if (bx < 3584) {
        // ---- cvtX: f32 -> bf16 ----
        int base = (bx - 3072) * 8192 + tid * 4;
#pragma unroll
        for (int j = 0; j < 8; j++) {
            float4 fx = *(const float4*)(X + base + j * 1024);
            uint2 o; o.x = pack2(fx.x, fx.y); o.y = pack2(fx.z, fx.w);
            *(uint2*)(Xb + base + j * 1024) = o;
        }
    } else {
        // ---- router + bucket ----
        int t = (bx - 3584) * 256 + tid;
        float4 a = *(const float4*)(RL + t * NEXP);
        float4 b = *(const float4*)(RL + t * NEXP + 4);
        float l[NEXP] = {a.x, a.y, a.z, a.w, b.x, b.y, b.z, b.w};
        int i0 = 0;
#pragma unroll
        for (int q = 1; q < NEXP; q++) if (l[q] > l[i0]) i0 = q;
        int i1 = (i0 == 0) ? 1 : 0;
#pragma unroll
        for (int q = 0; q < NEXP; q++) if (q != i0 && l[q] > l[i1]) i1 = q;
        float w0 = 1.0f / (1.0f + expf(l[i1] - l[i0]));
        ids[2 * t] = i0;     ids[2 * t + 1] = i1;
        wts[2 * t] = w0;     wts[2 * t + 1] = 1.0f - w0;
        int p0 = atomicAdd(&counts[i0], 1);
        rowbuf[i0 * MAXPE + p0] = 2 * t;
        int p1 = atomicAdd(&counts[i1], 1);
        rowbuf[i1 * MAXPE + p1] = 2 * t + 1;
    }
}

// ---------------- grouped GEMM, BM=256, 8 waves, counted-vmcnt dbuf ----------
// Doubled row-tile halves B staging traffic per FLOP (GEMM1 was L2-BW-bound:
// 2 GB staged at 34.5 TB/s aggregate L2 ~= the observed 70 us). Per wave:
// 4 A-regions + 2 B-regions staged per buffer (vmcnt(6) counted), output
// 32 rows x 128 cols (same fragment code as BM=128 version).
// PHASE1: A=Xb (row=grow>>1), B=WtU; 64 gate + 64 up cols; silu*u -> H (bf16).
// PHASE2: A=Hbuf (row=grow), B=WtD; 128-col tile; bf16 store.
template<int PHASE>
__global__ __launch_bounds__(512)
void mfma_gemm(const u16* __restrict__ A, const u16* __restrict__ Bt,
               u16* __restrict__ H,
               const int* __restrict__ counts, const int* __restrict__ rowbuf) {
    __shared__ __align__(16) u16 smem[49152];    // A0(32K)|B0(16K)|A1|B1 = 96 KB
    __shared__ int srid[256];
    const int bi = blockIdx.x;
    const int xcd = bi & 7, kb = bi >> 3;
    int e, ct, rt;
    if (PHASE == 1) { int p = (kb & 15) * 8 + xcd; e = p >> 4; ct = p & 15; rt = kb >> 4; }
    else            { int p = (kb & 7) * 8 + xcd;  e = p >> 3; ct = p & 7;  rt = kb >> 3; }
    const int cnt = counts[e];
    if (rt * 256 >= cnt) return;
    const int tid = threadIdx.x;
    const int lane = tid & 63, wave = tid >> 6;  // 8 waves

    u16* sA0 = smem;                 // [row][k] 256x64, no pad (global_load_lds)
    u16* sB0 = smem + 16384;         // [n][k] 128x64
    u16* sA1 = smem + 24576;
    u16* sB1 = smem + 40960;

    if (tid < 256) {
        int idx = rt * 256 + tid;
        srid[tid] = (idx < cnt) ? rowbuf[e * MAXPE + idx] : -1;
    }
    __syncthreads();                 // full drain entering the loop

    const int lrow = lane >> 3;
    const int lchunk = (lane & 7) ^ lrow;        // XOR bank swizzle, gather side
    const u16* aPtr[4]; const u16* bPtr[2];
    int aOff[4], bOff[2];
#pragma unroll
    for (int p = 0; p < 4; p++) {                // A: 32 regions of 8 rows
        int region = p * 8 + wave;
        int r = region * 8 + lrow;               // 0..255
        int rid = srid[r];
        int arow = (rid < 0) ? 0 : (PHASE == 1 ? (rid >> 1) : rid);
        aPtr[p] = A + (size_t)arow * 1024 + lchunk * 8;
        aOff[p] = region * 512 + lane * 8;
    }
#pragma unroll
    for (int p = 0; p < 2; p++) {                // B: 16 regions of 8 rows
        int region = p * 8 + wave;
        int r = region * 8 + lrow;               // 0..127
        int n;
        if (PHASE == 1) n = (r < 64) ? (ct * 64 + r) : (1024 + ct * 64 + (r - 64));
        else            n = ct * 128 + r;
        bPtr[p] = Bt + (size_t)e * (PHASE == 1 ? 2048 : 1024) * 1024
                     + (size_t)n * 1024 + lchunk * 8;
        bOff[p] = region * 512 + lane * 8;
    }

    const int quad = lane >> 4, mr = lane & 15;
    const int swA = mr & 7;
    const v4f zf = {0.f, 0.f, 0.f, 0.f};
    v4f acc[2][8];
#pragma unroll
    for (int i = 0; i < 2; i++)
#pragma unroll
        for (int j = 0; j < 8; j++) acc[i][j] = zf;

    auto stageAll = [&](u16* sAx, u16* sBx, int kk) {
#pragma unroll
        for (int p = 0; p < 4; p++) stage16(aPtr[p] + kk * 64, sAx + aOff[p]);
#pragma unroll
        for (int p = 0; p < 2; p++) stage16(bPtr[p] + kk * 64, sBx + bOff[p]);
    };
    auto computeTile = [&](const u16* sAx, const u16* sBx) {
#pragma unroll
        for (int kh = 0; kh < 2; kh++) {
            const int c = kh * 4 + quad;
            v8s a0 = *(const v8s*)(sAx + (wave * 32 + mr) * 64 + ((c ^ swA) * 8));
            v8s a1 = *(const v8s*)(sAx + (wave * 32 + 16 + mr) * 64 + ((c ^ swA) * 8));
#pragma unroll
            for (int nf = 0; nf < 8; nf++) {
                v8s b = *(const v8s*)(sBx + (nf * 16 + mr) * 64 + ((c ^ swA) * 8));
                acc[0][nf] = __builtin_amdgcn_mfma_f32_16x16x32_bf16(a0, b, acc[0][nf], 0, 0, 0);
                acc[1][nf] = __builtin_amdgcn_mfma_f32_16x16x32_bf16(a1, b, acc[1][nf], 0, 0, 0);
            }
        }
    };

    // ---- pipelined K-loop: 16 K-steps (BK=64), dbuf, counted vmcnt(6) ----
    stageAll(sA0, sB0, 0);                       // 6 loads/wave in flight
#pragma unroll 1
    for (int kt = 0; kt < 8; kt++) {
        stageAll(sA1, sB1, 2 * kt + 1);          // +6 -> 12 in flight
        asm volatile("s_waitcnt vmcnt(6)" ::: "memory");   // buf0 landed
        __builtin_amdgcn_s_barrier();
        computeTile(sA0, sB0);
        __builtin_amdgcn_s_barrier();            // all done reading buf0
        if (kt < 7) {
            stageAll(sA0, sB0, 2 * kt + 2);
            asm volatile("s_waitcnt vmcnt(6)" ::: "memory");
        } else {
            asm volatile("s_waitcnt vmcnt(0)" ::: "memory");
        }
        __builtin_amdgcn_s_barrier();
        computeTile(sA1, sB1);
        __builtin_amdgcn_s_barrier();
    }

    // C/D layout: col = lane&15, row = quad*4+reg
#pragma unroll
    for (int mf = 0; mf < 2; mf++) {
#pragma unroll
        for (int reg = 0; reg < 4; reg++) {
            int rl = wave * 32 + mf * 16 + quad * 4 + reg;
            int grow = srid[rl];
            if (grow < 0) continue;
            if (PHASE == 1) {
                size_t base = (size_t)grow * 1024 + ct * 64 + mr;
#pragma unroll
                for (int nf = 0; nf < 4; nf++) {
                    float g = acc[mf][nf][reg], u = acc[mf][nf + 4][reg];
                    H[base + nf * 16] = f2b((g / (1.0f + expf(-g))) * u);
                }
            } else {
                size_t base = (size_t)grow * 1024 + ct * 128 + mr;
#pragma unroll
                for (int nf = 0; nf < 8; nf++)
                    H[base + nf * 16] = f2b(acc[mf][nf][reg]);
            }
        }
    }
}

// ---------------- combine: out(f32)[t] = w0*acc[2t] + w1*acc[2t+1] ----------------
__global__ void combine_kernel(const u16* __restrict__ accb,
                               const float* __restrict__ wts,
                               float* __restrict__ out) {
    int g = blockIdx.x * blockDim.x + threadIdx.x;
    int t = g >> 8;
    int c = (g & 255) * 4;
    float w0 = wts[2 * t], w1 = wts[2 * t + 1];
    ushort4 a = *(const ushort4*)(accb + (size_t)(2 * t) * 1024 + c);
    ushort4 b = *(const ushort4*)(accb + (size_t)(2 * t + 1) * 1024 + c);
    float4 o;
    o.x = w0 * b2f(a.x) + w1 * b2f(b.x);
    o.y = w0 * b2f(a.y) + w1 * b2f(b.y);
    o.z = w0 * b2f(a.z) + w1 * b2f(b.z);
    o.w = w0 * b2f(a.w) + w1 * b2f(b.w);
    *(float4*)(out + (size_t)t * 1024 + c) = o;
}

// ================= R5 fallback path =================
__global__ void router_kernel(const float* __restrict__ logits,
                              int* __restrict__ ids, float* __restrict__ wts) {
    int t = blockIdx.x * blockDim.x + threadIdx.x;
    if (t >= T_TOK) return;
    float4 a = *(const float4*)(logits + t * NEXP);
    float4 b = *(const float4*)(logits + t * NEXP + 4);
    float l[NEXP] = {a.x, a.y, a.z, a.w, b.x, b.y, b.z, b.w};
    int i0 = 0;
#pragma unroll
    for (int i = 1; i < NEXP; i++) if (l[i] > l[i0]) i0 = i;
    int i1 = (i0 == 0) ? 1 : 0;
#pragma unroll
    for (int i = 0; i < NEXP; i++) if (i != i0 && l[i] > l[i1]) i1 = i;
    float w0 = 1.0f / (1.0f + expf(l[i1] - l[i0]));
    ids[2 * t] = i0;     ids[2 * t + 1] = i1;
    wts[2 * t] = w0;     wts[2 * t + 1] = 1.0f - w0;
}

__global__ void bucket_kernel(const int* __restrict__ ids,
                              int* __restrict__ counts, int* __restrict__ rowbuf) {
    int r = blockIdx.x * blockDim.x + threadIdx.x;
    if (r >= RROWS) return;
    int e = ids[r];
    int pos = atomicAdd(&counts[e], 1);
    rowbuf[e * MAXPE + pos] = r;
}

template<int GATED, int AF32>
__global__ __launch_bounds__(256)
void moe_gemm_kernel(const void* __restrict__ Av,
                     const float* __restrict__ B,
                     u16* __restrict__ C,
                     const int* __restrict__ counts,
                     const int* __restrict__ rowbuf,
                     int rowShift, int NB) {
    const int e   = blockIdx.z;
    const int cnt = counts[e];
    const int rt  = blockIdx.y;
    if (rt * 128 >= cnt) return;
    const int ct  = blockIdx.x;
    const int tid = threadIdx.x;

    __shared__ __align__(16) u16 sA[128 * 40];
    __shared__ __align__(16) u16 sB[(GATED ? 2 : 1) * 64 * 40];
    __shared__ int srid[128];

    if (tid < 128) {
        int idx = rt * 128 + tid;
        srid[tid] = (idx < cnt) ? rowbuf[e * MAXPE + idx] : -1;
    }
    __syncthreads();

    const int ar = tid >> 1, ac = (tid & 1) * 16;
    int arid = srid[ar];
    const float* aSrcF = 0; const u16* aSrcH = 0;
    if (arid >= 0) {
        if (AF32) aSrcF = (const float*)Av + (size_t)(arid >> rowShift) * HDIM + ac;
        else      aSrcH = (const u16*)Av + (size_t)(arid >> rowShift) * HDIM + ac;
    }
    u16* aDst = sA + ar * 40 + ac;

    const int kq2 = (tid >> 4) * 2, n4 = (tid & 15) * 4;
    const float* bSrcG = B + (size_t)e * 1024 * NB + (size_t)kq2 * NB + ct * 64 + n4;
    const float* bSrcU = bSrcG + 1024;

    const int lane = tid & 63, wave = tid >> 6;
    const int quad = lane >> 4, mr = lane & 15;

    const v4f zf = {0.f, 0.f, 0.f, 0.f};
    v4f accG[2][4], accU[2][4];
#pragma unroll
    for (int i = 0; i < 2; i++)
#pragma unroll
        for (int j = 0; j < 4; j++) { accG[i][j] = zf; accU[i][j] = zf; }

    for (int kk = 0; kk < HDIM / 32; kk++) {
        uint4 aw0 = make_uint4(0, 0, 0, 0), aw1 = make_uint4(0, 0, 0, 0);
        if (AF32) {
            if (aSrcF) {
                float4 f0 = *(const float4*)(aSrcF + kk * 32);
                float4 f1 = *(const float4*)(aSrcF + kk * 32 + 4);
                float4 f2 = *(const float4*)(aSrcF + kk * 32 + 8);
                float4 f3 = *(const float4*)(aSrcF + kk * 32 + 12);
                aw0 = make_uint4(pack2(f0.x, f0.y), pack2(f0.z, f0.w),
                                 pack2(f1.x, f1.y), pack2(f1.z, f1.w));
                aw1 = make_uint4(pack2(f2.x, f2.y), pack2(f2.z, f2.w),
                                 pack2(f3.x, f3.y), pack2(f3.z, f3.w));
            }
        } else {
            if (aSrcH) {
                aw0 = *(const uint4*)(aSrcH + kk * 32);
                aw1 = *(const uint4*)(aSrcH + kk * 32 + 8);
            }
        }
        const size_t bOff = (size_t)kk * 32 * NB;
        float4 g0 = *(const float4*)(bSrcG + bOff);
        float4 g1 = *(const float4*)(bSrcG + bOff + NB);
        float4 u0 = make_float4(0, 0, 0, 0), u1 = make_float4(0, 0, 0, 0);
        if (GATED) {
            u0 = *(const float4*)(bSrcU + bOff);
            u1 = *(const float4*)(bSrcU + bOff + NB);
        }

        __syncthreads();
        *(uint4*)aDst = aw0;
        *(uint4*)(aDst + 8) = aw1;
        {
            const float gx[4] = {g0.x, g0.y, g0.z, g0.w};
            const float gy[4] = {g1.x, g1.y, g1.z, g1.w};
#pragma unroll
            for (int j = 0; j < 4; j++)
                *(unsigned int*)&sB[(n4 + j) * 40 + kq2] = pack2(gx[j], gy[j]);
            if (GATED) {
                const float ux[4] = {u0.x, u0.y, u0.z, u0.w};
                const float uy[4] = {u1.x, u1.y, u1.z, u1.w};
#pragma unroll
                for (int j = 0; j < 4; j++)
                    *(unsigned int*)&sB[64 * 40 + (n4 + j) * 40 + kq2] = pack2(ux[j], uy[j]);
            }
        }
        __syncthreads();

        v8s af0 = *(const v8s*)(sA + (wave * 32 + mr) * 40 + quad * 8);
        v8s af1 = *(const v8s*)(sA + (wave * 32 + 16 + mr) * 40 + quad * 8);
#pragma unroll
        for (int nf = 0; nf < 4; nf++) {
            v8s bg = *(const v8s*)(sB + (nf * 16 + mr) * 40 + quad * 8);
            accG[0][nf] = __builtin_amdgcn_mfma_f32_16x16x32_bf16(af0, bg, accG[0][nf], 0, 0, 0);
            accG[1][nf] = __builtin_amdgcn_mfma_f32_16x16x32_bf16(af1, bg, accG[1][nf], 0, 0, 0);
            if (GATED) {
                v8s bu = *(const v8s*)(sB + 64 * 40 + (nf * 16 + mr) * 40 + quad * 8);
                accU[0][nf] = __builtin_amdgcn_mfma_f32_16x16x32_bf16(af0, bu, accU[0][nf], 0, 0, 0);
                accU[1][nf] = __builtin_amdgcn_mfma_f32_16x16x32_bf16(af1, bu, accU[1][nf], 0, 0, 0);
            }
        }
    }

#pragma unroll
    for (int mf = 0; mf < 2; mf++) {
#pragma unroll
        for (int reg = 0; reg < 4; reg++) {
            int rl = wave * 32 + mf * 16 + quad * 4 + reg;
            int grow = srid[rl];
            if (grow < 0) continue;
            size_t base = (size_t)grow * 1024 + ct * 64 + mr;
#pragma unroll
            for (int nf = 0; nf < 4; nf++) {
                float g = accG[mf][nf][reg];
                float val;
                if (GATED) {
                    float u = accU[mf][nf][reg];
                    val = (g / (1.0f + expf(-g))) * u;
                } else {
                    val = g;
                }
                C[base + nf * 16] = f2b(val);
            }
        }
    }
}

extern "C" void kernel_launch(void* const* d_in, const int* in_sizes, int n_in,
                              void* d_out, int out_size, void* d_ws, size_t ws_size,
                              hipStream_t stream) {
    const float *X = 0, *RL = 0, *WU = 0, *WD = 0;
    for (int i = 0; i < n_in; i++) {
        switch (in_sizes[i]) {
            case T_TOK * HDIM:        X  = (const float*)d_in[i]; break;
            case T_TOK * NEXP:        RL = (const float*)d_in[i]; break;
            case NEXP * HDIM * 2048:  WU = (const float*)d_in[i]; break;
            case NEXP * HDIM * 1024:  WD = (const float*)d_in[i]; break;
            default: break;
        }
    }
    if (!X)  X  = (const float*)d_in[0];
    if (!RL) RL = (const float*)d_in[1];
    if (!WU) WU = (const float*)d_in[2];
    if (!WD) WD = (const float*)d_in[3];
    float* OUT = (float*)d_out;

    char* ws = (char*)d_ws;
    int*   ids    = (int*)(ws + 0);
    float* wts    = (float*)(ws + 32768);
    int*   counts = (int*)(ws + 65536);
    int*   rowbuf = (int*)(ws + 65792);               // ends 196864
    u16* Xb   = (u16*)(ws + 196864);                  // 8 MB
    u16* WtU  = (u16*)(ws + 8585472);                 // 32 MB (dead after GEMM1)
    u16* WtD  = (u16*)(ws + 42139904);                // 16 MB
    u16* HbufF= (u16*)(ws + 58917120);                // 16 MB
    u16* AccF = WtU;                                  // 16 MB, aliases dead WtU
    const size_t needFast = 75694336ull;
    u16* Hbuf = (u16*)(ws + 196864);
    u16* Acc  = (u16*)(ws + 196864 + 16777216);

    hipMemsetAsync(counts, 0, NEXP * sizeof(int), stream);

    if (ws_size >= needFast) {
        prep_all<<<3600, 256, 0, stream>>>(
            X, RL, WU, WD, Xb, WtU, WtD, ids, wts, counts, rowbuf);
        mfma_gemm<1><<<2048, 512, 0, stream>>>(Xb, WtU, HbufF, counts, rowbuf);
        mfma_gemm<2><<<1024, 512, 0, stream>>>(HbufF, WtD, AccF, counts, rowbuf);
        combine_kernel<<<T_TOK, 256, 0, stream>>>(AccF, wts, OUT);
    } else {
        router_kernel<<<T_TOK / 256, 256, 0, stream>>>(RL, ids, wts);
        bucket_kernel<<<RROWS / 256, 256, 0, stream>>>(ids, counts, rowbuf);
        moe_gemm_kernel<1, 1><<<dim3(16, 32, NEXP), 256, 0, stream>>>(
            (const void*)X, WU, Hbuf, counts, rowbuf, 1, 2048);
        moe_gemm_kernel<0, 0><<<dim3(16, 32, NEXP), 256, 0, stream>>>(
            (const void*)Hbuf, WD, Acc, counts, rowbuf, 0, 1024);
        combine_kernel<<<T_TOK, 256, 0, stream>>>(Acc, wts, OUT);
    }
}

// Round 7
// 288.724 us; speedup vs baseline: 1.0334x; 1.0334x over previous
//
#include <hip/hip_runtime.h>
#include <hip/hip_bf16.h>

// MoE FFN: T=4096, H=I=1024, E=8, top-2. Inputs f32, output f32.
// Fast path (ws>=72.2MB): memset(counts) -> prep_all(cvtW -> pre-swizzled 8KB
// tile files, fully coalesced reads; cvtX; router) -> GEMM1 (gate+up+SiLU,
// BM=128, counted-vmcnt dbuf, linear tile-file B staging) -> Hbuf(bf16) ->
// GEMM2 (down, same) -> Acc(bf16, aliases dead WtU) -> combine(f32).
// Tile file format: per (e, nt, kt): 4096 u16 = the exact LDS image
// [region=n>>3][lane=(n&7)*8 + (c^(n&7))][8] for 64n x 64k (XOR swizzle baked).
// Fallback: R5 2-pass f32-staging path.

#define T_TOK 4096
#define HDIM  1024
#define NEXP  8
#define RROWS (T_TOK * 2)
#define MAXPE T_TOK

typedef unsigned short u16;
typedef short v8s __attribute__((ext_vector_type(8)));
typedef float v4f __attribute__((ext_vector_type(4)));
typedef __attribute__((address_space(3))) unsigned int as3_u32;
typedef const __attribute__((address_space(1))) unsigned int as1_u32c;

__device__ __forceinline__ float b2f(u16 u) {
    union { unsigned int i; float f; } v; v.i = ((unsigned int)u) << 16; return v.f;
}
__device__ __forceinline__ u16 f2b(float f) {
    union { float f; unsigned int i; } v; v.f = f;
    unsigned int x = v.i;
    return (u16)((x + 0x7FFFu + ((x >> 16) & 1u)) >> 16);
}
__device__ __forceinline__ unsigned int pack2(float a, float b) {
    return (unsigned int)f2b(a) | ((unsigned int)f2b(b) << 16);
}
__device__ __forceinline__ void stage16(const u16* g, u16* l) {
    __builtin_amdgcn_global_load_lds((as1_u32c*)g, (as3_u32*)l, 16, 0, 0);
}

// ---------------- prep_all ----------------
// blocks 0..1023:    cvtWU (64k x 256n staged tiles -> 4 output tiles each)
// blocks 1024..1535: cvtWD (same, N=1024)
// blocks 1536..2047: cvtX
// blocks 2048..2063: router + bucket
// cvtW: stage 64k x 256n f32 via global_load_lds -- each instruction reads ONE
// contiguous 1KB k-row (max DRAM burst efficiency). Column read-out is
// conflict-free by construction (lane = n, consecutive addresses). Output is
// the pre-swizzled tile file; each thread owns one 128B lane-row per tile.
__global__ __launch_bounds__(256)
void prep_all(const float* __restrict__ X, const float* __restrict__ RL,
              const float* __restrict__ WU, const float* __restrict__ WD,
              u16* __restrict__ Xb, u16* __restrict__ WtU, u16* __restrict__ WtD,
              int* __restrict__ ids, float* __restrict__ wts,
              int* __restrict__ counts, int* __restrict__ rowbuf) {
    __shared__ __align__(16) float smf[64 * 256];    // 64 KB f32 tile [k][n]
    const int bx = blockIdx.x;
    const int tid = threadIdx.x;

    if (bx < 1536) {
        const float* Wb; u16* Wtb; int N, NT, e, nb, kb;
        if (bx < 1024) {
            e = bx >> 7; int r = bx & 127;           // 8 n-blocks x 16 k-blocks
            nb = r >> 4; kb = r & 15;
            Wb = WU + (size_t)e * 1024 * 2048; Wtb = WtU; N = 2048; NT = 32;
        } else {
            int b = bx - 1024;
            e = b >> 6; int r = b & 63;              // 4 n-blocks x 16 k-blocks
            nb = r >> 4; kb = r & 15;
            Wb = WD + (size_t)e * 1024 * 1024; Wtb = WtD; N = 1024; NT = 16;
        }
        const int n0 = nb * 256, k0 = kb * 64;
        const int wv = tid >> 6, l = tid & 63;
        // stage: 16 contiguous 1KB k-rows per wave
#pragma unroll
        for (int i = 0; i < 16; i++) {
            int k = wv * 16 + i;
            stage16((const u16*)(Wb + (size_t)(k0 + k) * N + n0) + l * 8,
                    (u16*)smf + k * 512 + l * 8);
        }
        __syncthreads();                             // drains vmcnt, tile ready
        // read-out: thread = one n-column; 8 chunks of 8 k each
        const int n_l = tid;                         // 0..255
        const int tile_n = n_l >> 6, n_in = n_l & 63;
        const int lrow = n_in & 7;
        u16* tbase = Wtb + ((size_t)(e * NT + nb * 4 + tile_n) * 16 + kb) * 4096
                   + (n_in >> 3) * 512 + lrow * 64;
#pragma unroll
        for (int c = 0; c < 8; c++) {                // k-chunk
            float v[8];
#pragma unroll
            for (int j = 0; j < 8; j++) v[j] = smf[(c * 8 + j) * 256 + n_l];
            uint4 o;
            o.x = pack2(v[0], v[1]); o.y = pack2(v[2], v[3]);
            o.z = pack2(v[4], v[5]); o.w = pack2(v[6], v[7]);
            *(uint4*)(tbase + (c ^ lrow) * 8) = o;   // XOR swizzle baked in file
        }
    } else if (bx < 2048) {
        // ---- cvtX: f32 -> bf16, contiguous streaming ----
        int base = (bx - 1536) * 8192 + tid * 4;
#pragma unroll
        for (int j = 0; j < 8; j++) {
            float4 fx = *(const float4*)(X + base + j * 1024);
            uint2 o; o.x = pack2(fx.x, fx.y); o.y = pack2(fx.z, fx.w);
            *(uint2*)(Xb + base + j * 1024) = o;
        }
    } else {
        // ---- router + bucket ----
        int t = (bx - 2048) * 256 + tid;
        float4 a = *(const float4*)(RL + t * NEXP);
        float4 b = *(const float4*)(RL + t * NEXP + 4);
        float l[NEXP] = {a.x, a.y, a.z, a.w, b.x, b.y, b.z, b.w};
        int i0 = 0;
#pragma unroll
        for (int q = 1; q < NEXP; q++) if (l[q] > l[i0]) i0 = q;
        int i1 = (i0 == 0) ? 1 : 0;
#pragma unroll
        for (int q = 0; q < NEXP; q++) if (q != i0 && l[q] > l[i1]) i1 = q;
        float w0 = 1.0f / (1.0f + expf(l[i1] - l[i0]));
        ids[2 * t] = i0;     ids[2 * t + 1] = i1;
        wts[2 * t] = w0;     wts[2 * t + 1] = 1.0f - w0;
        int p0 = atomicAdd(&counts[i0], 1);
        rowbuf[i0 * MAXPE + p0] = 2 * t;
        int p1 = atomicAdd(&counts[i1], 1);
        rowbuf[i1 * MAXPE + p1] = 2 * t + 1;
    }
}

// ---------------- grouped GEMM, BM=128, counted-vmcnt dbuf ----------------
// B is fetched from the pre-swizzled tile file: fully linear 1KB/wave/region,
// tile stride 4096 u16 per K-step. LDS image identical to the proven compute
// loop's expectation (XOR chunk swizzle baked at prep time). A is gathered
// per-token with source-side XOR (rows scattered by routing).
// PHASE1: 4096 blocks; A=Xb (row=grow>>1), B=WtU tiles (gate nt=ct, up
//         nt=16+ct); epilogue silu*u -> H (bf16).
// PHASE2: 2048 blocks; A=Hbuf (row=grow), B=WtD tiles (nt=2ct,2ct+1); bf16.
template<int PHASE>
__global__ __launch_bounds__(256)
void mfma_gemm(const u16* __restrict__ A, const u16* __restrict__ Bt,
               u16* __restrict__ H,
               const int* __restrict__ counts, const int* __restrict__ rowbuf) {
    __shared__ __align__(16) u16 smem[4 * 128 * 64];   // sA0|sB0|sA1|sB1, 64KB
    __shared__ int srid[128];
    const int bi = blockIdx.x;
    const int xcd = bi & 7, kb = bi >> 3;
    int e, ct, rt;
    if (PHASE == 1) { int p = (kb & 15) * 8 + xcd; e = p >> 4; ct = p & 15; rt = kb >> 4; }
    else            { int p = (kb & 7) * 8 + xcd;  e = p >> 3; ct = p & 7;  rt = kb >> 3; }
    const int cnt = counts[e];
    if (rt * 128 >= cnt) return;
    const int tid = threadIdx.x;
    const int lane = tid & 63, wave = tid >> 6;

    u16* sA0 = smem;                 // [row][k], no pad (global_load_lds)
    u16* sB0 = smem + 8192;          // [n][k] pre-swizzled image
    u16* sA1 = smem + 16384;
    u16* sB1 = smem + 24576;

    if (tid < 128) {
        int idx = rt * 128 + tid;
        srid[tid] = (idx < cnt) ? rowbuf[e * MAXPE + idx] : -1;
    }
    __syncthreads();                 // full drain: vmcnt=0 entering the loop

    const int lrow = lane >> 3;
    const int lchunk = (lane & 7) ^ lrow;        // XOR swizzle, A gather side
    const u16* aPtr[4]; const u16* bPtr[4];
    int offs[4];
#pragma unroll
    for (int p = 0; p < 4; p++) {
        int region = p * 4 + wave;               // 16 regions of 8 rows
        int r = region * 8 + lrow;
        int rid = srid[r];
        int arow = (rid < 0) ? 0 : (PHASE == 1 ? (rid >> 1) : rid);
        aPtr[p] = A + (size_t)arow * 1024 + lchunk * 8;
        int nt;                                   // B tile index for this region
        if (PHASE == 1) nt = (region < 8) ? ct : (16 + ct);          // NT=32
        else            nt = ct * 2 + (region >> 3);                 // NT=16
        bPtr[p] = Bt + ((size_t)(e * (PHASE == 1 ? 32 : 16) + nt) * 16) * 4096
                     + (region & 7) * 512 + lane * 8;                // linear!
        offs[p] = region * 512 + lane * 8;
    }

    const int quad = lane >> 4, mr = lane & 15;
    const int swA = mr & 7;
    const v4f zf = {0.f, 0.f, 0.f, 0.f};
    v4f acc[2][8];
#pragma unroll
    for (int i = 0; i < 2; i++)
#pragma unroll
        for (int j = 0; j < 8; j++) acc[i][j] = zf;

    auto stageAll = [&](u16* sAx, u16* sBx, int kk) {
#pragma unroll
        for (int p = 0; p < 4; p++) {
            stage16(aPtr[p] + kk * 64, sAx + offs[p]);       // A: row stride
            stage16(bPtr[p] + kk * 4096, sBx + offs[p]);     // B: tile stride
        }
    };
    auto computeTile = [&](const u16* sAx, const u16* sBx) {
#pragma unroll
        for (int kh = 0; kh < 2; kh++) {
            const int c = kh * 4 + quad;
            v8s a0 = *(const v8s*)(sAx + (wave * 32 + mr) * 64 + ((c ^ swA) * 8));
            v8s a1 = *(const v8s*)(sAx + (wave * 32 + 16 + mr) * 64 + ((c ^ swA) * 8));
#pragma unroll
            for (int nf = 0; nf < 8; nf++) {
                v8s b = *(const v8s*)(sBx + (nf * 16 + mr) * 64 + ((c ^ swA) * 8));
                acc[0][nf] = __builtin_amdgcn_mfma_f32_16x16x32_bf16(a0, b, acc[0][nf], 0, 0, 0);
                acc[1][nf] = __builtin_amdgcn_mfma_f32_16x16x32_bf16(a1, b, acc[1][nf], 0, 0, 0);
            }
        }
    };

    // ---- pipelined K-loop: 16 K-steps (BK=64), dbuf, counted vmcnt ----
    stageAll(sA0, sB0, 0);                       // 8 loads/wave in flight
#pragma unroll 1
    for (int kt = 0; kt < 8; kt++) {
        stageAll(sA1, sB1, 2 * kt + 1);          // +8 -> 16 in flight
        asm volatile("s_waitcnt vmcnt(8)" ::: "memory");   // buf0 landed
        __builtin_amdgcn_s_barrier();
        computeTile(sA0, sB0);
        __builtin_amdgcn_s_barrier();            // all done reading buf0
        if (kt < 7) {
            stageAll(sA0, sB0, 2 * kt + 2);
            asm volatile("s_waitcnt vmcnt(8)" ::: "memory");
        } else {
            asm volatile("s_waitcnt vmcnt(0)" ::: "memory");
        }
        __builtin_amdgcn_s_barrier();
        computeTile(sA1, sB1);
        __builtin_amdgcn_s_barrier();
    }

    // C/D layout: col = lane&15, row = quad*4+reg
#pragma unroll
    for (int mf = 0; mf < 2; mf++) {
#pragma unroll
        for (int reg = 0; reg < 4; reg++) {
            int rl = wave * 32 + mf * 16 + quad * 4 + reg;
            int grow = srid[rl];
            if (grow < 0) continue;
            if (PHASE == 1) {
                size_t base = (size_t)grow * 1024 + ct * 64 + mr;
#pragma unroll
                for (int nf = 0; nf < 4; nf++) {
                    float g = acc[mf][nf][reg], u = acc[mf][nf + 4][reg];
                    H[base + nf * 16] = f2b((g / (1.0f + expf(-g))) * u);
                }
            } else {
                size_t base = (size_t)grow * 1024 + ct * 128 + mr;
#pragma unroll
                for (int nf = 0; nf < 8; nf++)
                    H[base + nf * 16] = f2b(acc[mf][nf][reg]);
            }
        }
    }
}

// ---------------- combine: out(f32)[t] = w0*acc[2t] + w1*acc[2t+1] ----------------
__global__ void combine_kernel(const u16* __restrict__ accb,
                               const float* __restrict__ wts,
                               float* __restrict__ out) {
    int g = blockIdx.x * blockDim.x + threadIdx.x;
    int t = g >> 8;
    int c = (g & 255) * 4;
    float w0 = wts[2 * t], w1 = wts[2 * t + 1];
    ushort4 a = *(const ushort4*)(accb + (size_t)(2 * t) * 1024 + c);
    ushort4 b = *(const ushort4*)(accb + (size_t)(2 * t + 1) * 1024 + c);
    float4 o;
    o.x = w0 * b2f(a.x) + w1 * b2f(b.x);
    o.y = w0 * b2f(a.y) + w1 * b2f(b.y);
    o.z = w0 * b2f(a.z) + w1 * b2f(b.z);
    o.w = w0 * b2f(a.w) + w1 * b2f(b.w);
    *(float4*)(out + (size_t)t * 1024 + c) = o;
}

// ================= R5 fallback path =================
__global__ void router_kernel(const float* __restrict__ logits,
                              int* __restrict__ ids, float* __restrict__ wts) {
    int t = blockIdx.x * blockDim.x + threadIdx.x;
    if (t >= T_TOK) return;
    float4 a = *(const float4*)(logits + t * NEXP);
    float4 b = *(const float4*)(logits + t * NEXP + 4);
    float l[NEXP] = {a.x, a.y, a.z, a.w, b.x, b.y, b.z, b.w};
    int i0 = 0;
#pragma unroll
    for (int i = 1; i < NEXP; i++) if (l[i] > l[i0]) i0 = i;
    int i1 = (i0 == 0) ? 1 : 0;
#pragma unroll
    for (int i = 0; i < NEXP; i++) if (i != i0 && l[i] > l[i1]) i1 = i;
    float w0 = 1.0f / (1.0f + expf(l[i1] - l[i0]));
    ids[2 * t] = i0;     ids[2 * t + 1] = i1;
    wts[2 * t] = w0;     wts[2 * t + 1] = 1.0f - w0;
}

__global__ void bucket_kernel(const int* __restrict__ ids,
                              int* __restrict__ counts, int* __restrict__ rowbuf) {
    int r = blockIdx.x * blockDim.x + threadIdx.x;
    if (r >= RROWS) return;
    int e = ids[r];
    int pos = atomicAdd(&counts[e], 1);
    rowbuf[e * MAXPE + pos] = r;
}

template<int GATED, int AF32>
__global__ __launch_bounds__(256)
void moe_gemm_kernel(const void* __restrict__ Av,
                     const float* __restrict__ B,
                     u16* __restrict__ C,
                     const int* __restrict__ counts,
                     const int* __restrict__ rowbuf,
                     int rowShift, int NB) {
    const int e   = blockIdx.z;
    const int cnt = counts[e];
    const int rt  = blockIdx.y;
    if (rt * 128 >= cnt) return;
    const int ct  = blockIdx.x;
    const int tid = threadIdx.x;

    __shared__ __align__(16) u16 sA[128 * 40];
    __shared__ __align__(16) u16 sB[(GATED ? 2 : 1) * 64 * 40];
    __shared__ int srid[128];

    if (tid < 128) {
        int idx = rt * 128 + tid;
        srid[tid] = (idx < cnt) ? rowbuf[e * MAXPE + idx] : -1;
    }
    __syncthreads();

    const int ar = tid >> 1, ac = (tid & 1) * 16;
    int arid = srid[ar];
    const float* aSrcF = 0; const u16* aSrcH = 0;
    if (arid >= 0) {
        if (AF32) aSrcF = (const float*)Av + (size_t)(arid >> rowShift) * HDIM + ac;
        else      aSrcH = (const u16*)Av + (size_t)(arid >> rowShift) * HDIM + ac;
    }
    u16* aDst = sA + ar * 40 + ac;

    const int kq2 = (tid >> 4) * 2, n4 = (tid & 15) * 4;
    const float* bSrcG = B + (size_t)e * 1024 * NB + (size_t)kq2 * NB + ct * 64 + n4;
    const float* bSrcU = bSrcG + 1024;

    const int lane = tid & 63, wave = tid >> 6;
    const int quad = lane >> 4, mr = lane & 15;

    const v4f zf = {0.f, 0.f, 0.f, 0.f};
    v4f accG[2][4], accU[2][4];
#pragma unroll
    for (int i = 0; i < 2; i++)
#pragma unroll
        for (int j = 0; j < 4; j++) { accG[i][j] = zf; accU[i][j] = zf; }

    for (int kk = 0; kk < HDIM / 32; kk++) {
        uint4 aw0 = make_uint4(0, 0, 0, 0), aw1 = make_uint4(0, 0, 0, 0);
        if (AF32) {
            if (aSrcF) {
                float4 f0 = *(const float4*)(aSrcF + kk * 32);
                float4 f1 = *(const float4*)(aSrcF + kk * 32 + 4);
                float4 f2 = *(const float4*)(aSrcF + kk * 32 + 8);
                float4 f3 = *(const float4*)(aSrcF + kk * 32 + 12);
                aw0 = make_uint4(pack2(f0.x, f0.y), pack2(f0.z, f0.w),
                                 pack2(f1.x, f1.y), pack2(f1.z, f1.w));
                aw1 = make_uint4(pack2(f2.x, f2.y), pack2(f2.z, f2.w),
                                 pack2(f3.x, f3.y), pack2(f3.z, f3.w));
            }
        } else {
            if (aSrcH) {
                aw0 = *(const uint4*)(aSrcH + kk * 32);
                aw1 = *(const uint4*)(aSrcH + kk * 32 + 8);
            }
        }
        const size_t bOff = (size_t)kk * 32 * NB;
        float4 g0 = *(const float4*)(bSrcG + bOff);
        float4 g1 = *(const float4*)(bSrcG + bOff + NB);
        float4 u0 = make_float4(0, 0, 0, 0), u1 = make_float4(0, 0, 0, 0);
        if (GATED) {
            u0 = *(const float4*)(bSrcU + bOff);
            u1 = *(const float4*)(bSrcU + bOff + NB);
        }

        __syncthreads();
        *(uint4*)aDst = aw0;
        *(uint4*)(aDst + 8) = aw1;
        {
            const float gx[4] = {g0.x, g0.y, g0.z, g0.w};
            const float gy[4] = {g1.x, g1.y, g1.z, g1.w};
#pragma unroll
            for (int j = 0; j < 4; j++)
                *(unsigned int*)&sB[(n4 + j) * 40 + kq2] = pack2(gx[j], gy[j]);
            if (GATED) {
                const float ux[4] = {u0.x, u0.y, u0.z, u0.w};
                const float uy[4] = {u1.x, u1.y, u1.z, u1.w};
#pragma unroll
                for (int j = 0; j < 4; j++)
                    *(unsigned int*)&sB[64 * 40 + (n4 + j) * 40 + kq2] = pack2(ux[j], uy[j]);
            }
        }
        __syncthreads();

        v8s af0 = *(const v8s*)(sA + (wave * 32 + mr) * 40 + quad * 8);
        v8s af1 = *(const v8s*)(sA + (wave * 32 + 16 + mr) * 40 + quad * 8);
#pragma unroll
        for (int nf = 0; nf < 4; nf++) {
            v8s bg = *(const v8s*)(sB + (nf * 16 + mr) * 40 + quad * 8);
            accG[0][nf] = __builtin_amdgcn_mfma_f32_16x16x32_bf16(af0, bg, accG[0][nf], 0, 0, 0);
            accG[1][nf] = __builtin_amdgcn_mfma_f32_16x16x32_bf16(af1, bg, accG[1][nf], 0, 0, 0);
            if (GATED) {
                v8s bu = *(const v8s*)(sB + 64 * 40 + (nf * 16 + mr) * 40 + quad * 8);
                accU[0][nf] = __builtin_amdgcn_mfma_f32_16x16x32_bf16(af0, bu, accU[0][nf], 0, 0, 0);
                accU[1][nf] = __builtin_amdgcn_mfma_f32_16x16x32_bf16(af1, bu, accU[1][nf], 0, 0, 0);
            }
        }
    }

#pragma unroll
    for (int mf = 0; mf < 2; mf++) {
#pragma unroll
        for (int reg = 0; reg < 4; reg++) {
            int rl = wave * 32 + mf * 16 + quad * 4 + reg;
            int grow = srid[rl];
            if (grow < 0) continue;
            size_t base = (size_t)grow * 1024 + ct * 64 + mr;
#pragma unroll
            for (int nf = 0; nf < 4; nf++) {
                float g = accG[mf][nf][reg];
                float val;
                if (GATED) {
                    float u = accU[mf][nf][reg];
                    val = (g / (1.0f + expf(-g))) * u;
                } else {
                    val = g;
                }
                C[base + nf * 16] = f2b(val);
            }
        }
    }
}

extern "C" void kernel_launch(void* const* d_in, const int* in_sizes, int n_in,
                              void* d_out, int out_size, void* d_ws, size_t ws_size,
                              hipStream_t stream) {
    const float *X = 0, *RL = 0, *WU = 0, *WD = 0;
    for (int i = 0; i < n_in; i++) {
        switch (in_sizes[i]) {
            case T_TOK * HDIM:        X  = (const float*)d_in[i]; break;
            case T_TOK * NEXP:        RL = (const float*)d_in[i]; break;
            case NEXP * HDIM * 2048:  WU = (const float*)d_in[i]; break;
            case NEXP * HDIM * 1024:  WD = (const float*)d_in[i]; break;
            default: break;
        }
    }
    if (!X)  X  = (const float*)d_in[0];
    if (!RL) RL = (const float*)d_in[1];
    if (!WU) WU = (const float*)d_in[2];
    if (!WD) WD = (const float*)d_in[3];
    float* OUT = (float*)d_out;

    char* ws = (char*)d_ws;
    int*   ids    = (int*)(ws + 0);
    float* wts    = (float*)(ws + 32768);
    int*   counts = (int*)(ws + 65536);
    int*   rowbuf = (int*)(ws + 65792);               // ends 196864
    u16* Xb   = (u16*)(ws + 196864);                  // 8 MB
    u16* WtU  = (u16*)(ws + 8585472);                 // 32 MB (dead after GEMM1)
    u16* WtD  = (u16*)(ws + 42139904);                // 16 MB
    u16* HbufF= (u16*)(ws + 58917120);                // 16 MB
    u16* AccF = WtU;                                  // 16 MB, aliases dead WtU
    const size_t needFast = 75694336ull;
    u16* Hbuf = (u16*)(ws + 196864);
    u16* Acc  = (u16*)(ws + 196864 + 16777216);

    hipMemsetAsync(counts, 0, NEXP * sizeof(int), stream);

    if (ws_size >= needFast) {
        prep_all<<<2064, 256, 0, stream>>>(
            X, RL, WU, WD, Xb, WtU, WtD, ids, wts, counts, rowbuf);
        mfma_gemm<1><<<4096, 256, 0, stream>>>(Xb, WtU, HbufF, counts, rowbuf);
        mfma_gemm<2><<<2048, 256, 0, stream>>>(HbufF, WtD, AccF, counts, rowbuf);
        combine_kernel<<<T_TOK, 256, 0, stream>>>(AccF, wts, OUT);
    } else {
        router_kernel<<<T_TOK / 256, 256, 0, stream>>>(RL, ids, wts);
        bucket_kernel<<<RROWS / 256, 256, 0, stream>>>(ids, counts, rowbuf);
        moe_gemm_kernel<1, 1><<<dim3(16, 32, NEXP), 256, 0, stream>>>(
            (const void*)X, WU, Hbuf, counts, rowbuf, 1, 2048);
        moe_gemm_kernel<0, 0><<<dim3(16, 32, NEXP), 256, 0, stream>>>(
            (const void*)Hbuf, WD, Acc, counts, rowbuf, 0, 1024);
        combine_kernel<<<T_TOK, 256, 0, stream>>>(Acc, wts, OUT);
    }
}

// Round 8
// 266.941 us; speedup vs baseline: 1.1177x; 1.0816x over previous
//
#include <hip/hip_runtime.h>
#include <hip/hip_bf16.h>

// MoE FFN: T=4096, H=I=1024, E=8, top-2. Inputs f32, output f32.
// R0 baseline (best measured: 264-265us) with ONE change: GEMM block-order
// swizzle makes rt the FASTEST index per (e,ct) panel, panel pinned to one
// XCD. Concurrent B working set per XCD drops 4MB -> 256KB => B panels stay
// L2-resident across their rt sweep (GEMM1 FETCH was 102MB vs 48MB floor).
// Pipeline: memset(counts) -> prep_all(cvtW + cvtX + router, one kernel) ->
// GEMM1 (gate+up+SiLU) -> Hbuf(bf16) -> GEMM2 (down) -> Acc(bf16, aliases
// dead WtU) -> combine(f32). Fallback: R5 2-pass f32-staging path.

#define T_TOK 4096
#define HDIM  1024
#define NEXP  8
#define RROWS (T_TOK * 2)
#define MAXPE T_TOK

typedef unsigned short u16;
typedef short v8s __attribute__((ext_vector_type(8)));
typedef float v4f __attribute__((ext_vector_type(4)));
typedef __attribute__((address_space(3))) unsigned int as3_u32;
typedef const __attribute__((address_space(1))) unsigned int as1_u32c;

__device__ __forceinline__ float b2f(u16 u) {
    union { unsigned int i; float f; } v; v.i = ((unsigned int)u) << 16; return v.f;
}
__device__ __forceinline__ u16 f2b(float f) {
    union { float f; unsigned int i; } v; v.f = f;
    unsigned int x = v.i;
    return (u16)((x + 0x7FFFu + ((x >> 16) & 1u)) >> 16);
}
__device__ __forceinline__ unsigned int pack2(float a, float b) {
    return (unsigned int)f2b(a) | ((unsigned int)f2b(b) << 16);
}
__device__ __forceinline__ void stage16(const u16* g, u16* l) {
    __builtin_amdgcn_global_load_lds((as1_u32c*)g, (as3_u32*)l, 16, 0, 0);
}

// ---------------- prep_all: cvtW (blocks 0..6143) + cvtX (6144..10239)
//                  + router/bucket (10240..10255), one launch ----------------
__global__ __launch_bounds__(256)
void prep_all(const float* __restrict__ X, const float* __restrict__ RL,
              const float* __restrict__ WU, const float* __restrict__ WD,
              u16* __restrict__ Xb, u16* __restrict__ WtU, u16* __restrict__ WtD,
              int* __restrict__ ids, float* __restrict__ wts,
              int* __restrict__ counts, int* __restrict__ rowbuf) {
    __shared__ __align__(16) u16 tile[64 * 72];
    const int bx = blockIdx.x;
    const int tid = threadIdx.x;

    if (bx < 6144) {
        // ---- cvtW: W[e][1024k][N] f32 -> Wt[e][N][1024k] bf16 ----
        int e = bx / 768;
        int r2 = bx - e * 768;
        int ky = r2 / 48;
        int bxx = r2 - ky * 48;
        const float* Wb; u16* Wtb; int N;
        if (bxx < 32) { Wb = WU + (size_t)e * 1024 * 2048; Wtb = WtU + (size_t)e * 2048 * 1024; N = 2048; }
        else          { Wb = WD + (size_t)e * 1024 * 1024; Wtb = WtD + (size_t)e * 1024 * 1024; N = 1024; bxx -= 32; }
        int n0 = bxx * 64, k0 = ky * 64;
        int r = tid >> 4, c4 = (tid & 15) * 4;
#pragma unroll
        for (int j = 0; j < 4; j++) {
            int k = r + j * 16;
            float4 f = *(const float4*)(Wb + (size_t)(k0 + k) * N + n0 + c4);
            tile[(c4 + 0) * 72 + k] = f2b(f.x);
            tile[(c4 + 1) * 72 + k] = f2b(f.y);
            tile[(c4 + 2) * 72 + k] = f2b(f.z);
            tile[(c4 + 3) * 72 + k] = f2b(f.w);
        }
        __syncthreads();
        int n = tid >> 2, kc = (tid & 3) * 16;
        uint4 v0 = *(const uint4*)&tile[n * 72 + kc];
        uint4 v1 = *(const uint4*)&tile[n * 72 + kc + 8];
        u16* dst = Wtb + (size_t)(n0 + n) * 1024 + k0 + kc;
        *(uint4*)dst = v0;
        *(uint4*)(dst + 8) = v1;
    } else if (bx < 10240) {
        // ---- cvtX: f32 -> bf16 ----
        int i = ((bx - 6144) * 256 + tid) * 4;
        float4 f = *(const float4*)(X + i);
        uint2 o; o.x = pack2(f.x, f.y); o.y = pack2(f.z, f.w);
        *(uint2*)(Xb + i) = o;
    } else {
        // ---- router + bucket ----
        int t = (bx - 10240) * 256 + tid;
        float4 a = *(const float4*)(RL + t * NEXP);
        float4 b = *(const float4*)(RL + t * NEXP + 4);
        float l[NEXP] = {a.x, a.y, a.z, a.w, b.x, b.y, b.z, b.w};
        int i0 = 0;
#pragma unroll
        for (int q = 1; q < NEXP; q++) if (l[q] > l[i0]) i0 = q;
        int i1 = (i0 == 0) ? 1 : 0;
#pragma unroll
        for (int q = 0; q < NEXP; q++) if (q != i0 && l[q] > l[i1]) i1 = q;
        float w0 = 1.0f / (1.0f + expf(l[i1] - l[i0]));
        ids[2 * t] = i0;     ids[2 * t + 1] = i1;
        wts[2 * t] = w0;     wts[2 * t + 1] = 1.0f - w0;
        int p0 = atomicAdd(&counts[i0], 1);
        rowbuf[i0 * MAXPE + p0] = 2 * t;
        int p1 = atomicAdd(&counts[i1], 1);
        rowbuf[i1 * MAXPE + p1] = 2 * t + 1;
    }
}

// ---------------- grouped GEMM, global_load_lds + XOR swizzle ----------------
// Block-order: panel (e,ct) pinned to one XCD; rt is the FASTEST index so a
// panel's entire rt sweep runs consecutively on that XCD => B panel (256KB)
// stays L2-resident, read from HBM once (was: 16 panels = 4MB concurrent = L2
// thrash, FETCH 102MB vs 48MB floor).
// PHASE1: 4096 blocks; A=Xb (row=grow>>1), B=WtU; dual 64-col gate/up tile;
//         epilogue silu*u -> H (bf16).
// PHASE2: 2048 blocks; A=Hbuf (row=grow), B=WtD; 128-col tile; bf16 store.
template<int PHASE>
__global__ __launch_bounds__(256)
void mfma_gemm(const u16* __restrict__ A, const u16* __restrict__ Bt,
               u16* __restrict__ H,
               const int* __restrict__ counts, const int* __restrict__ rowbuf) {
    const int bi = blockIdx.x;
    const int xcd = bi & 7, kb = bi >> 3;
    int e, ct, rt;
    if (PHASE == 1) {
        int pl = kb >> 5; rt = kb & 31;          // rt fast; 16 panels/xcd
        int p = pl * 8 + xcd;                    // panel id 0..127
        e = p >> 4; ct = p & 15;
    } else {
        int pl = kb >> 5; rt = kb & 31;          // rt fast; 8 panels/xcd
        e = pl; ct = xcd;                        // ct pinned to xcd
    }
    const int cnt = counts[e];
    if (rt * 128 >= cnt) return;
    const int tid = threadIdx.x;
    const int lane = tid & 63, wave = tid >> 6;

    __shared__ __align__(16) u16 sA[128 * 64];   // [row][k], no pad (global_load_lds)
    __shared__ __align__(16) u16 sB[128 * 64];   // [n][k]
    __shared__ int srid[128];

    if (tid < 128) {
        int idx = rt * 128 + tid;
        srid[tid] = (idx < cnt) ? rowbuf[e * MAXPE + idx] : -1;
    }
    __syncthreads();

    const int lrow = lane >> 3;
    const int lchunk = (lane & 7) ^ lrow;        // XOR bank swizzle on gather side
    const u16* aPtr[4]; const u16* bPtr[4];
    u16 *aDst[4], *bDst[4];
#pragma unroll
    for (int p = 0; p < 4; p++) {
        int region = p * 4 + wave;
        int r = region * 8 + lrow;
        int rid = srid[r];
        int arow = (rid < 0) ? 0 : (PHASE == 1 ? (rid >> 1) : rid);
        aPtr[p] = A + (size_t)arow * 1024 + lchunk * 8;
        aDst[p] = sA + region * 512 + lane * 8;
        int n;
        if (PHASE == 1) n = (r < 64) ? (ct * 64 + r) : (1024 + ct * 64 + (r - 64));
        else            n = ct * 128 + r;
        bPtr[p] = Bt + (size_t)e * (PHASE == 1 ? 2048 : 1024) * 1024
                     + (size_t)n * 1024 + lchunk * 8;
        bDst[p] = sB + region * 512 + lane * 8;
    }

    const int quad = lane >> 4, mr = lane & 15;
    const int swA = mr & 7;
    const v4f zf = {0.f, 0.f, 0.f, 0.f};
    v4f acc[2][8];
#pragma unroll
    for (int i = 0; i < 2; i++)
#pragma unroll
        for (int j = 0; j < 8; j++) acc[i][j] = zf;

    for (int kk = 0; kk < 16; kk++) {            // BK=64
        __syncthreads();
#pragma unroll
        for (int p = 0; p < 4; p++) {
            stage16(aPtr[p] + kk * 64, aDst[p]);
            stage16(bPtr[p] + kk * 64, bDst[p]);
        }
        __syncthreads();
#pragma unroll
        for (int kh = 0; kh < 2; kh++) {
            const int c = kh * 4 + quad;
            v8s a0 = *(const v8s*)(sA + (wave * 32 + mr) * 64 + ((c ^ swA) * 8));
            v8s a1 = *(const v8s*)(sA + (wave * 32 + 16 + mr) * 64 + ((c ^ swA) * 8));
#pragma unroll
            for (int nf = 0; nf < 8; nf++) {
                v8s b = *(const v8s*)(sB + (nf * 16 + mr) * 64 + ((c ^ swA) * 8));
                acc[0][nf] = __builtin_amdgcn_mfma_f32_16x16x32_bf16(a0, b, acc[0][nf], 0, 0, 0);
                acc[1][nf] = __builtin_amdgcn_mfma_f32_16x16x32_bf16(a1, b, acc[1][nf], 0, 0, 0);
            }
        }
    }

    // C/D layout: col = lane&15, row = quad*4+reg
#pragma unroll
    for (int mf = 0; mf < 2; mf++) {
#pragma unroll
        for (int reg = 0; reg < 4; reg++) {
            int rl = wave * 32 + mf * 16 + quad * 4 + reg;
            int grow = srid[rl];
            if (grow < 0) continue;
            if (PHASE == 1) {
                size_t base = (size_t)grow * 1024 + ct * 64 + mr;
#pragma unroll
                for (int nf = 0; nf < 4; nf++) {
                    float g = acc[mf][nf][reg], u = acc[mf][nf + 4][reg];
                    H[base + nf * 16] = f2b((g / (1.0f + expf(-g))) * u);
                }
            } else {
                size_t base = (size_t)grow * 1024 + ct * 128 + mr;
#pragma unroll
                for (int nf = 0; nf < 8; nf++)
                    H[base + nf * 16] = f2b(acc[mf][nf][reg]);
            }
        }
    }
}

// ---------------- combine: out(f32)[t] = w0*acc[2t] + w1*acc[2t+1] ----------------
__global__ void combine_kernel(const u16* __restrict__ accb,
                               const float* __restrict__ wts,
                               float* __restrict__ out) {
    int g = blockIdx.x * blockDim.x + threadIdx.x;
    int t = g >> 8;
    int c = (g & 255) * 4;
    float w0 = wts[2 * t], w1 = wts[2 * t + 1];
    ushort4 a = *(const ushort4*)(accb + (size_t)(2 * t) * 1024 + c);
    ushort4 b = *(const ushort4*)(accb + (size_t)(2 * t + 1) * 1024 + c);
    float4 o;
    o.x = w0 * b2f(a.x) + w1 * b2f(b.x);
    o.y = w0 * b2f(a.y) + w1 * b2f(b.y);
    o.z = w0 * b2f(a.z) + w1 * b2f(b.z);
    o.w = w0 * b2f(a.w) + w1 * b2f(b.w);
    *(float4*)(out + (size_t)t * 1024 + c) = o;
}

// ================= R5 fallback path =================
__global__ void router_kernel(const float* __restrict__ logits,
                              int* __restrict__ ids, float* __restrict__ wts) {
    int t = blockIdx.x * blockDim.x + threadIdx.x;
    if (t >= T_TOK) return;
    float4 a = *(const float4*)(logits + t * NEXP);
    float4 b = *(const float4*)(logits + t * NEXP + 4);
    float l[NEXP] = {a.x, a.y, a.z, a.w, b.x, b.y, b.z, b.w};
    int i0 = 0;
#pragma unroll
    for (int i = 1; i < NEXP; i++) if (l[i] > l[i0]) i0 = i;
    int i1 = (i0 == 0) ? 1 : 0;
#pragma unroll
    for (int i = 0; i < NEXP; i++) if (i != i0 && l[i] > l[i1]) i1 = i;
    float w0 = 1.0f / (1.0f + expf(l[i1] - l[i0]));
    ids[2 * t] = i0;     ids[2 * t + 1] = i1;
    wts[2 * t] = w0;     wts[2 * t + 1] = 1.0f - w0;
}

__global__ void bucket_kernel(const int* __restrict__ ids,
                              int* __restrict__ counts, int* __restrict__ rowbuf) {
    int r = blockIdx.x * blockDim.x + threadIdx.x;
    if (r >= RROWS) return;
    int e = ids[r];
    int pos = atomicAdd(&counts[e], 1);
    rowbuf[e * MAXPE + pos] = r;
}

template<int GATED, int AF32>
__global__ __launch_bounds__(256)
void moe_gemm_kernel(const void* __restrict__ Av,
                     const float* __restrict__ B,
                     u16* __restrict__ C,
                     const int* __restrict__ counts,
                     const int* __restrict__ rowbuf,
                     int rowShift, int NB) {
    const int e   = blockIdx.z;
    const int cnt = counts[e];
    const int rt  = blockIdx.y;
    if (rt * 128 >= cnt) return;
    const int ct  = blockIdx.x;
    const int tid = threadIdx.x;

    __shared__ __align__(16) u16 sA[128 * 40];
    __shared__ __align__(16) u16 sB[(GATED ? 2 : 1) * 64 * 40];
    __shared__ int srid[128];

    if (tid < 128) {
        int idx = rt * 128 + tid;
        srid[tid] = (idx < cnt) ? rowbuf[e * MAXPE + idx] : -1;
    }
    __syncthreads();

    const int ar = tid >> 1, ac = (tid & 1) * 16;
    int arid = srid[ar];
    const float* aSrcF = 0; const u16* aSrcH = 0;
    if (arid >= 0) {
        if (AF32) aSrcF = (const float*)Av + (size_t)(arid >> rowShift) * HDIM + ac;
        else      aSrcH = (const u16*)Av + (size_t)(arid >> rowShift) * HDIM + ac;
    }
    u16* aDst = sA + ar * 40 + ac;

    const int kq2 = (tid >> 4) * 2, n4 = (tid & 15) * 4;
    const float* bSrcG = B + (size_t)e * 1024 * NB + (size_t)kq2 * NB + ct * 64 + n4;
    const float* bSrcU = bSrcG + 1024;

    const int lane = tid & 63, wave = tid >> 6;
    const int quad = lane >> 4, mr = lane & 15;

    const v4f zf = {0.f, 0.f, 0.f, 0.f};
    v4f accG[2][4], accU[2][4];
#pragma unroll
    for (int i = 0; i < 2; i++)
#pragma unroll
        for (int j = 0; j < 4; j++) { accG[i][j] = zf; accU[i][j] = zf; }

    for (int kk = 0; kk < HDIM / 32; kk++) {
        uint4 aw0 = make_uint4(0, 0, 0, 0), aw1 = make_uint4(0, 0, 0, 0);
        if (AF32) {
            if (aSrcF) {
                float4 f0 = *(const float4*)(aSrcF + kk * 32);
                float4 f1 = *(const float4*)(aSrcF + kk * 32 + 4);
                float4 f2 = *(const float4*)(aSrcF + kk * 32 + 8);
                float4 f3 = *(const float4*)(aSrcF + kk * 32 + 12);
                aw0 = make_uint4(pack2(f0.x, f0.y), pack2(f0.z, f0.w),
                                 pack2(f1.x, f1.y), pack2(f1.z, f1.w));
                aw1 = make_uint4(pack2(f2.x, f2.y), pack2(f2.z, f2.w),
                                 pack2(f3.x, f3.y), pack2(f3.z, f3.w));
            }
        } else {
            if (aSrcH) {
                aw0 = *(const uint4*)(aSrcH + kk * 32);
                aw1 = *(const uint4*)(aSrcH + kk * 32 + 8);
            }
        }
        const size_t bOff = (size_t)kk * 32 * NB;
        float4 g0 = *(const float4*)(bSrcG + bOff);
        float4 g1 = *(const float4*)(bSrcG + bOff + NB);
        float4 u0 = make_float4(0, 0, 0, 0), u1 = make_float4(0, 0, 0, 0);
        if (GATED) {
            u0 = *(const float4*)(bSrcU + bOff);
            u1 = *(const float4*)(bSrcU + bOff + NB);
        }

        __syncthreads();
        *(uint4*)aDst = aw0;
        *(uint4*)(aDst + 8) = aw1;
        {
            const float gx[4] = {g0.x, g0.y, g0.z, g0.w};
            const float gy[4] = {g1.x, g1.y, g1.z, g1.w};
#pragma unroll
            for (int j = 0; j < 4; j++)
                *(unsigned int*)&sB[(n4 + j) * 40 + kq2] = pack2(gx[j], gy[j]);
            if (GATED) {
                const float ux[4] = {u0.x, u0.y, u0.z, u0.w};
                const float uy[4] = {u1.x, u1.y, u1.z, u1.w};
#pragma unroll
                for (int j = 0; j < 4; j++)
                    *(unsigned int*)&sB[64 * 40 + (n4 + j) * 40 + kq2] = pack2(ux[j], uy[j]);
            }
        }
        __syncthreads();

        v8s af0 = *(const v8s*)(sA + (wave * 32 + mr) * 40 + quad * 8);
        v8s af1 = *(const v8s*)(sA + (wave * 32 + 16 + mr) * 40 + quad * 8);
#pragma unroll
        for (int nf = 0; nf < 4; nf++) {
            v8s bg = *(const v8s*)(sB + (nf * 16 + mr) * 40 + quad * 8);
            accG[0][nf] = __builtin_amdgcn_mfma_f32_16x16x32_bf16(af0, bg, accG[0][nf], 0, 0, 0);
            accG[1][nf] = __builtin_amdgcn_mfma_f32_16x16x32_bf16(af1, bg, accG[1][nf], 0, 0, 0);
            if (GATED) {
                v8s bu = *(const v8s*)(sB + 64 * 40 + (nf * 16 + mr) * 40 + quad * 8);
                accU[0][nf] = __builtin_amdgcn_mfma_f32_16x16x32_bf16(af0, bu, accU[0][nf], 0, 0, 0);
                accU[1][nf] = __builtin_amdgcn_mfma_f32_16x16x32_bf16(af1, bu, accU[1][nf], 0, 0, 0);
            }
        }
    }

#pragma unroll
    for (int mf = 0; mf < 2; mf++) {
#pragma unroll
        for (int reg = 0; reg < 4; reg++) {
            int rl = wave * 32 + mf * 16 + quad * 4 + reg;
            int grow = srid[rl];
            if (grow < 0) continue;
            size_t base = (size_t)grow * 1024 + ct * 64 + mr;
#pragma unroll
            for (int nf = 0; nf < 4; nf++) {
                float g = accG[mf][nf][reg];
                float val;
                if (GATED) {
                    float u = accU[mf][nf][reg];
                    val = (g / (1.0f + expf(-g))) * u;
                } else {
                    val = g;
                }
                C[base + nf * 16] = f2b(val);
            }
        }
    }
}

extern "C" void kernel_launch(void* const* d_in, const int* in_sizes, int n_in,
                              void* d_out, int out_size, void* d_ws, size_t ws_size,
                              hipStream_t stream) {
    const float *X = 0, *RL = 0, *WU = 0, *WD = 0;
    for (int i = 0; i < n_in; i++) {
        switch (in_sizes[i]) {
            case T_TOK * HDIM:        X  = (const float*)d_in[i]; break;
            case T_TOK * NEXP:        RL = (const float*)d_in[i]; break;
            case NEXP * HDIM * 2048:  WU = (const float*)d_in[i]; break;
            case NEXP * HDIM * 1024:  WD = (const float*)d_in[i]; break;
            default: break;
        }
    }
    if (!X)  X  = (const float*)d_in[0];
    if (!RL) RL = (const float*)d_in[1];
    if (!WU) WU = (const float*)d_in[2];
    if (!WD) WD = (const float*)d_in[3];
    float* OUT = (float*)d_out;

    char* ws = (char*)d_ws;
    int*   ids    = (int*)(ws + 0);
    float* wts    = (float*)(ws + 32768);
    int*   counts = (int*)(ws + 65536);
    int*   rowbuf = (int*)(ws + 65792);               // ends 196864
    u16* Xb   = (u16*)(ws + 196864);                  // 8 MB
    u16* WtU  = (u16*)(ws + 8585472);                 // 32 MB (dead after GEMM1)
    u16* WtD  = (u16*)(ws + 42139904);                // 16 MB
    u16* HbufF= (u16*)(ws + 58917120);                // 16 MB
    u16* AccF = WtU;                                  // 16 MB, aliases dead WtU
    const size_t needFast = 75694336ull;
    u16* Hbuf = (u16*)(ws + 196864);
    u16* Acc  = (u16*)(ws + 196864 + 16777216);

    hipMemsetAsync(counts, 0, NEXP * sizeof(int), stream);

    if (ws_size >= needFast) {
        prep_all<<<10256, 256, 0, stream>>>(
            X, RL, WU, WD, Xb, WtU, WtD, ids, wts, counts, rowbuf);
        mfma_gemm<1><<<4096, 256, 0, stream>>>(Xb, WtU, HbufF, counts, rowbuf);
        mfma_gemm<2><<<2048, 256, 0, stream>>>(HbufF, WtD, AccF, counts, rowbuf);
        combine_kernel<<<T_TOK, 256, 0, stream>>>(AccF, wts, OUT);
    } else {
        router_kernel<<<T_TOK / 256, 256, 0, stream>>>(RL, ids, wts);
        bucket_kernel<<<RROWS / 256, 256, 0, stream>>>(ids, counts, rowbuf);
        moe_gemm_kernel<1, 1><<<dim3(16, 32, NEXP), 256, 0, stream>>>(
            (const void*)X, WU, Hbuf, counts, rowbuf, 1, 2048);
        moe_gemm_kernel<0, 0><<<dim3(16, 32, NEXP), 256, 0, stream>>>(
            (const void*)Hbuf, WD, Acc, counts, rowbuf, 0, 1024);
        combine_kernel<<<T_TOK, 256, 0, stream>>>(Acc, wts, OUT);
    }
}